// Round 1
// baseline (364.854 us; speedup 1.0000x reference)
//
#include <hip/hip_runtime.h>
#include <math.h>

#define Bn 512
#define Ln 20
#define Nn 100
#define Dn 64
#define En 32
#define Hn 3

// ---------------- K0: transpose prep ----------------
__global__ __launch_bounds__(256) void k0_prep(
    const float* __restrict__ Wu_r, const float* __restrict__ Wi_r,
    const float* __restrict__ Wu_w, const float* __restrict__ Wi_w,
    const float* __restrict__ M_w,
    const float* __restrict__ Wu_f, const float* __restrict__ Wi_f,
    const float* __restrict__ ufc, const float* __restrict__ ifc,
    const float* __restrict__ ufc2, const float* __restrict__ ifc2,
    float* __restrict__ WuT_r, float* __restrict__ WiT_r,
    float* __restrict__ WuT_w, float* __restrict__ WiT_w,
    float* __restrict__ MT_w,
    float* __restrict__ WuT_f, float* __restrict__ WiT_f,
    float* __restrict__ ufcT, float* __restrict__ ifcT,
    float* __restrict__ u_fcT, float* __restrict__ i_fcT)
{
    int t = blockIdx.x * blockDim.x + threadIdx.x;
    int stride = gridDim.x * blockDim.x;
    for (int k = t; k < Hn*Dn*Dn; k += stride) {
        int h = k / (Dn*Dn); int rem = k - h*Dn*Dn;
        int a = rem >> 6, c = rem & 63;
        int src = h*Dn*Dn + c*Dn + a;            // T[h][a][c] = W[h][c][a]
        WuT_r[k] = Wu_r[src]; WiT_r[k] = Wi_r[src];
        WuT_w[k] = Wu_w[src]; WiT_w[k] = Wi_w[src];
        MT_w[k]  = M_w[src];
    }
    for (int k = t; k < Hn*En*En; k += stride) {
        int h = k / (En*En); int rem = k - h*En*En;
        int a = rem >> 5, c = rem & 31;
        int src = h*En*En + c*En + a;
        WuT_f[k] = Wu_f[src]; WiT_f[k] = Wi_f[src];
    }
    for (int k = t; k < Dn*En; k += stride) {    // ufcT[d*32+e] = ufc[e*64+d]
        int d = k >> 5, e = k & 31;
        ufcT[k] = ufc[e*Dn + d]; ifcT[k] = ifc[e*Dn + d];
    }
    for (int k = t; k < 96*En; k += stride) {    // u_fcT[kk*32+e] = u_fc[e*96+kk]
        int kk = k >> 5, e = k & 31;
        u_fcT[k] = ufc2[e*96 + kk]; i_fcT[k] = ifc2[e*96 + kk];
    }
}

// ---------------- K1: review gate (gather-sum + gated MLP) ----------------
// 1 wave per (side, b, l); 4 waves per block.
__global__ __launch_bounds__(256) void k1_gate(
    const int* __restrict__ urev, const int* __restrict__ irev,
    const float* __restrict__ utab, const float* __restrict__ itab,
    const float* __restrict__ W1, const float* __restrict__ b1v,
    const float* __restrict__ W2, const float* __restrict__ b2v,
    float* __restrict__ ugo, float* __restrict__ igo)
{
    __shared__ float w1s[Dn][Dn+1];   // +1 pad: lanes read w1s[ln][d] -> 2-way banks, free
    __shared__ float w2s[Dn][Dn+1];
    __shared__ int   idxs[4][Nn];
    __shared__ float sbuf[4][Dn];
    int tid = threadIdx.x;
    for (int k = tid; k < Dn*Dn; k += 256) {
        int r = k >> 6, c = k & 63;
        w1s[r][c] = W1[k]; w2s[r][c] = W2[k];
    }
    int wv = tid >> 6, ln = tid & 63;
    int gw = blockIdx.x * 4 + wv;            // [0, 2*B*L)
    int side = gw / (Bn*Ln);
    int r = gw - side*(Bn*Ln);               // b*L + l
    const int* rev = side ? irev : urev;
    const float* tab = side ? itab : utab;
    for (int n = ln; n < Nn; n += 64) idxs[wv][n] = rev[r*Nn + n];
    __syncthreads();
    float acc = 0.f;
    #pragma unroll 4
    for (int n = 0; n < Nn; ++n) acc += tab[idxs[wv][n]*Dn + ln];
    sbuf[wv][ln] = acc;
    __syncthreads();
    float t1 = b1v[ln], t2 = b2v[ln];
    for (int d = 0; d < Dn; ++d) {
        float sv = sbuf[wv][d];
        t1 += sv * w1s[ln][d];
        t2 += sv * w2s[ln][d];
    }
    float g = (1.f / (1.f + expf(-t1))) * tanhf(t2);
    float* outp = side ? igo : ugo;
    outp[r*Dn + ln] = g;
}

// ---------------- K2: per-(b,h) full pipeline ----------------
__global__ __launch_bounds__(256) void k2_coatt(
    const int* __restrict__ urev, const int* __restrict__ irev,
    const int* __restrict__ uids, const int* __restrict__ iids,
    const int* __restrict__ ttype, const int* __restrict__ tmonth,
    const float* __restrict__ gu_all, const float* __restrict__ gi_all,
    const float* __restrict__ utab, const float* __restrict__ itab,
    const float* __restrict__ uid_tab, const float* __restrict__ iid_tab,
    const float* __restrict__ type_tab, const float* __restrict__ month_tab,
    const float* __restrict__ ug_in, const float* __restrict__ ig_in,
    const float* __restrict__ M_r, const float* __restrict__ bu_r, const float* __restrict__ bi_r,
    const float* __restrict__ WuT_r, const float* __restrict__ WiT_r,
    const float* __restrict__ Wu_w, const float* __restrict__ Wi_w, const float* __restrict__ M_w,
    const float* __restrict__ bu_w, const float* __restrict__ bi_w,
    const float* __restrict__ WuT_w, const float* __restrict__ WiT_w, const float* __restrict__ MT_w,
    const float* __restrict__ M_f, const float* __restrict__ bu_f, const float* __restrict__ bi_f,
    const float* __restrict__ WuT_f, const float* __restrict__ WiT_f,
    const float* __restrict__ ufcT, const float* __restrict__ ufc_bv,
    const float* __restrict__ ifcT, const float* __restrict__ ifc_bv,
    float* __restrict__ feas, float* __restrict__ outp)
{
    __shared__ union {
        struct {  // phase 1: co-attention over review gates (L x D)
            float ug[Ln][Dn+1], ig[Ln][Dn+1];
            float uu[Ln][Dn+1], Ab[Ln][Dn+1], iv[Ln][Dn+1];
        } p1;
        struct {  // phase 2: gathered words (N x D), padded for conflict-free row reads
            float uw[Nn][Dn+1], iw[Nn][Dn+1];
        } p2;
    } sh;
    __shared__ float S[Ln][Ln];
    __shared__ int   lstar[2];
    __shared__ int   idxs[2][Nn];
    __shared__ float vecs[8][Dn];   // uwbar,iwbar,ubar2,ibar2,v,q,wu,wi
    __shared__ float cuci[2];
    __shared__ float sc[2][Nn];
    __shared__ float uif[2][Dn];
    __shared__ float re[2][En], fe[4][En];
    __shared__ float u3[2][En], i3[4][En], A3[2][En];
    __shared__ float att[6];        // review_att[0:2], fea_att[2:6]

    int tid = threadIdx.x;
    int bh = blockIdx.x;
    int b = bh / Hn;
    int h = bh - b*Hn;

    // feature embedding (4 x 32) — needed only in phase 3
    if (tid < 4*En) {
        int rrow = tid >> 5, e = tid & 31;
        float v;
        if (rrow == 0) v = uid_tab[uids[b]*En + e];
        else if (rrow == 1) v = iid_tab[iids[b]*En + e];
        else if (rrow == 2) v = type_tab[ttype[b]*En + e];
        else v = month_tab[tmonth[b]*En + e];
        fe[rrow][e] = v;
    }
    for (int k = tid; k < Ln*Dn; k += 256) {
        int l = k >> 6, d = k & 63;
        sh.p1.ug[l][d] = ug_in[(b*Ln + l)*Dn + d];
        sh.p1.ig[l][d] = ig_in[(b*Ln + l)*Dn + d];
    }
    __syncthreads();
    // ---- phase 1: coatt_r (max pooling + gumbel argmax) ----
    const float* WuT = WuT_r + h*Dn*Dn;
    const float* WiT = WiT_r + h*Dn*Dn;
    const float* Mr  = M_r  + h*Dn*Dn;
    const float* bu  = bu_r + h*Dn;
    const float* bi  = bi_r + h*Dn;
    for (int k = tid; k < Ln*Dn; k += 256) {
        int l = k >> 6, dp = k & 63;
        float a1 = bu[dp], a2 = bi[dp];
        for (int d = 0; d < Dn; ++d) {
            a1 += sh.p1.ug[l][d] * WuT[d*Dn + dp];   // u = ug @ Wu^T + bu
            a2 += sh.p1.ig[l][d] * WiT[d*Dn + dp];   // i = ig @ Wi^T + bi
        }
        sh.p1.uu[l][dp] = a1;
        sh.p1.iv[l][dp] = a2;
    }
    __syncthreads();
    for (int k = tid; k < Ln*Dn; k += 256) {
        int l = k >> 6, e = k & 63;
        float a = 0.f;
        for (int d = 0; d < Dn; ++d) a += sh.p1.uu[l][d] * Mr[d*Dn + e];  // A = u @ M
        sh.p1.Ab[l][e] = a;
    }
    __syncthreads();
    for (int k = tid; k < Ln*Ln; k += 256) {
        int l = k / Ln, m = k - l*Ln;
        float a = 0.f;
        for (int e = 0; e < Dn; ++e) a += sh.p1.Ab[l][e] * sh.p1.iv[m][e];
        S[l][m] = a;
    }
    __syncthreads();
    if (tid == 0) {         // argmax_l(rowmax(S) + gumbel) — first-max tie-break
        const float* gu = gu_all + (h*Bn + b)*Ln;
        int bestl = 0; float bestv = -3.4e38f;
        for (int l = 0; l < Ln; ++l) {
            float mx = S[l][0];
            for (int m = 1; m < Ln; ++m) mx = fmaxf(mx, S[l][m]);
            float v = mx + gu[l];
            if (v > bestv) { bestv = v; bestl = l; }
        }
        lstar[0] = bestl;
    } else if (tid == 64) {
        const float* gi = gi_all + (h*Bn + b)*Ln;
        int bestm = 0; float bestv = -3.4e38f;
        for (int m = 0; m < Ln; ++m) {
            float mx = S[0][m];
            for (int l = 1; l < Ln; ++l) mx = fmaxf(mx, S[l][m]);
            float v = mx + gi[m];
            if (v > bestv) { bestv = v; bestm = m; }
        }
        lstar[1] = bestm;
    }
    __syncthreads();
    // ---- phase 2: gather selected review's words; coatt_w (avg pooling, folded) ----
    int lu = lstar[0], li = lstar[1];
    for (int n = tid; n < Nn; n += 256) {
        idxs[0][n] = urev[(b*Ln + lu)*Nn + n];
        idxs[1][n] = irev[(b*Ln + li)*Nn + n];
    }
    __syncthreads();
    for (int k = tid; k < Nn*Dn; k += 256) {
        int n = k >> 6, d = k & 63;
        sh.p2.uw[n][d] = utab[idxs[0][n]*Dn + d];
        sh.p2.iw[n][d] = itab[idxs[1][n]*Dn + d];
    }
    __syncthreads();
    if (tid < Dn) {                        // uwbar = mean_n uw
        float a = 0.f;
        for (int n = 0; n < Nn; ++n) a += sh.p2.uw[n][tid];
        vecs[0][tid] = a * (1.0f/Nn);
    } else if (tid < 2*Dn) {
        int d = tid - Dn;
        float a = 0.f;
        for (int n = 0; n < Nn; ++n) a += sh.p2.iw[n][d];
        vecs[1][d] = a * (1.0f/Nn);
    }
    __syncthreads();
    const float* WuTw = WuT_w + h*Dn*Dn;
    const float* WiTw = WiT_w + h*Dn*Dn;
    const float* MTw  = MT_w  + h*Dn*Dn;
    const float* Wuw  = Wu_w  + h*Dn*Dn;
    const float* Wiw  = Wi_w  + h*Dn*Dn;
    const float* Mw   = M_w   + h*Dn*Dn;
    const float* buw  = bu_w + h*Dn;
    const float* biw  = bi_w + h*Dn;
    if (tid < Dn) {                        // ubar2 = Wu@uwbar + bu
        float a = buw[tid];
        for (int d = 0; d < Dn; ++d) a += WuTw[d*Dn + tid] * vecs[0][d];
        vecs[2][tid] = a;
    } else if (tid < 2*Dn) {               // ibar2 = Wi@iwbar + bi
        int j = tid - Dn;
        float a = biw[j];
        for (int d = 0; d < Dn; ++d) a += WiTw[d*Dn + j] * vecs[1][d];
        vecs[3][j] = a;
    }
    __syncthreads();
    if (tid < Dn) {                        // v = M @ ibar2
        float a = 0.f;
        for (int e = 0; e < Dn; ++e) a += MTw[e*Dn + tid] * vecs[3][e];
        vecs[4][tid] = a;
    } else if (tid < 2*Dn) {               // q = M^T @ ubar2
        int e = tid - Dn;
        float a = 0.f;
        for (int d = 0; d < Dn; ++d) a += Mw[d*Dn + e] * vecs[2][d];
        vecs[5][e] = a;
    }
    __syncthreads();
    if (tid < Dn) {                        // wu = Wu^T v
        float a = 0.f;
        for (int j = 0; j < Dn; ++j) a += Wuw[j*Dn + tid] * vecs[4][j];
        vecs[6][tid] = a;
    } else if (tid < 2*Dn) {               // wi = Wi^T q
        int dp = tid - Dn;
        float a = 0.f;
        for (int j = 0; j < Dn; ++j) a += Wiw[j*Dn + dp] * vecs[5][j];
        vecs[7][dp] = a;
    } else if (tid == 2*Dn) {              // cu = bu·v
        float a = 0.f;
        for (int j = 0; j < Dn; ++j) a += buw[j] * vecs[4][j];
        cuci[0] = a;
    } else if (tid == 2*Dn + 1) {          // ci = bi·q
        float a = 0.f;
        for (int j = 0; j < Dn; ++j) a += biw[j] * vecs[5][j];
        cuci[1] = a;
    }
    __syncthreads();
    if (tid < Nn) {                        // u_score2[n] = uw[n]·wu + cu
        float a = cuci[0];
        for (int d = 0; d < Dn; ++d) a += sh.p2.uw[tid][d] * vecs[6][d];
        sc[0][tid] = a;
    } else if (tid >= 128 && tid < 128 + Nn) {
        int n = tid - 128;
        float a = cuci[1];
        for (int d = 0; d < Dn; ++d) a += sh.p2.iw[n][d] * vecs[7][d];
        sc[1][n] = a;
    }
    __syncthreads();
    if (tid == 0) {                        // softmax over N (u)
        float mx = -3.4e38f;
        for (int n = 0; n < Nn; ++n) mx = fmaxf(mx, sc[0][n]);
        float s = 0.f;
        for (int n = 0; n < Nn; ++n) { float e = expf(sc[0][n] - mx); sc[0][n] = e; s += e; }
        float inv = 1.f / s;
        for (int n = 0; n < Nn; ++n) sc[0][n] *= inv;
    } else if (tid == 128) {               // softmax over N (i)
        float mx = -3.4e38f;
        for (int n = 0; n < Nn; ++n) mx = fmaxf(mx, sc[1][n]);
        float s = 0.f;
        for (int n = 0; n < Nn; ++n) { float e = expf(sc[1][n] - mx); sc[1][n] = e; s += e; }
        float inv = 1.f / s;
        for (int n = 0; n < Nn; ++n) sc[1][n] *= inv;
    }
    __syncthreads();
    if (tid < Dn) {                        // u_w_fea = sum_n p_u2[n]*uw[n]
        float a = 0.f;
        for (int n = 0; n < Nn; ++n) a += sc[0][n] * sh.p2.uw[n][tid];
        uif[0][tid] = a;
    } else if (tid < 2*Dn) {               // i_w_fea = sum_n p_i2[n]*uw[n]  (reference quirk: uw!)
        int d = tid - Dn;
        float a = 0.f;
        for (int n = 0; n < Nn; ++n) a += sc[1][n] * sh.p2.uw[n][d];
        uif[1][d] = a;
    }
    __syncthreads();
    if (tid < En) {                        // ure = relu(ufc(u_w_fea))
        float a = ufc_bv[tid];
        for (int d = 0; d < Dn; ++d) a += uif[0][d] * ufcT[d*En + tid];
        re[0][tid] = fmaxf(a, 0.f);
    } else if (tid < 2*En) {               // ire = relu(ifc(i_w_fea))
        int e = tid - En;
        float a = ifc_bv[e];
        for (int d = 0; d < Dn; ++d) a += uif[1][d] * ifcT[d*En + e];
        re[1][e] = fmaxf(a, 0.f);
    }
    __syncthreads();
    // ---- phase 3: coatt_f (2x4, avg pooling) ----
    const float* WuTf = WuT_f + h*En*En;
    const float* WiTf = WiT_f + h*En*En;
    const float* Mf   = M_f  + h*En*En;
    const float* buf_ = bu_f + h*En;
    const float* bif_ = bi_f + h*En;
    if (tid < 2*En) {
        int l = tid >> 5, e = tid & 31;
        float a = buf_[e];
        for (int j = 0; j < En; ++j) a += re[l][j] * WuTf[j*En + e];
        u3[l][e] = a;
    } else if (tid < 6*En) {
        int t2 = tid - 2*En;
        int m = t2 >> 5, e = t2 & 31;
        float a = bif_[e];
        for (int j = 0; j < En; ++j) a += fe[m][j] * WiTf[j*En + e];
        i3[m][e] = a;
    }
    __syncthreads();
    if (tid < 2*En) {
        int l = tid >> 5, e = tid & 31;
        float a = 0.f;
        for (int d = 0; d < En; ++d) a += u3[l][d] * Mf[d*En + e];
        A3[l][e] = a;
    }
    __syncthreads();
    if (tid == 0) {
        float S3[2][4];
        for (int l = 0; l < 2; ++l)
            for (int m = 0; m < 4; ++m) {
                float a = 0.f;
                for (int e = 0; e < En; ++e) a += A3[l][e] * i3[m][e];
                S3[l][m] = a;
            }
        float us0 = (S3[0][0] + S3[0][1] + S3[0][2] + S3[0][3]) * 0.25f;
        float us1 = (S3[1][0] + S3[1][1] + S3[1][2] + S3[1][3]) * 0.25f;
        float mx = fmaxf(us0, us1);
        float e0 = expf(us0 - mx), e1 = expf(us1 - mx);
        float inv = 1.f / (e0 + e1);
        att[0] = e0 * inv; att[1] = e1 * inv;         // review_att
        float is_[4]; float mxi = -3.4e38f;
        for (int m = 0; m < 4; ++m) { is_[m] = (S3[0][m] + S3[1][m]) * 0.5f; mxi = fmaxf(mxi, is_[m]); }
        float ssum = 0.f, ee[4];
        for (int m = 0; m < 4; ++m) { ee[m] = expf(is_[m] - mxi); ssum += ee[m]; }
        float invi = 1.f / ssum;
        for (int m = 0; m < 4; ++m) att[2 + m] = ee[m] * invi;  // fea_att
    }
    __syncthreads();
    if (tid < En) {
        feas[b*96 + h*En + tid] = re[0][tid] * att[0];   // user_fea_h (appended to both u_feas & i_feas)
    }
    if (h == 2) {   // last iteration's fea_att-scaled features go straight to output
        if (tid >= 32 && tid < 64)        { int e = tid - 32;  outp[b*96 + e]            = fe[0][e] * att[2]; } // user_id_e
        else if (tid >= 64 && tid < 96)   { int e = tid - 64;  outp[b*96 + 32 + e]       = fe[2][e] * att[4]; } // type_e
        else if (tid >= 96 && tid < 128)  { int e = tid - 96;  outp[Bn*96 + b*96 + e]      = fe[1][e] * att[3]; } // item_id_e
        else if (tid >= 128 && tid < 160) { int e = tid - 128; outp[Bn*96 + b*96 + 32 + e] = fe[3][e] * att[5]; } // month_e
    }
}

// ---------------- K3: final linears ----------------
__global__ __launch_bounds__(64) void k3_final(
    const float* __restrict__ feas,
    const float* __restrict__ u_fcT, const float* __restrict__ u_fc_bv,
    const float* __restrict__ i_fcT, const float* __restrict__ i_fc_bv,
    float* __restrict__ outp)
{
    __shared__ float f[96];
    int b = blockIdx.x, tid = threadIdx.x;
    for (int k = tid; k < 96; k += 64) f[k] = feas[b*96 + k];
    __syncthreads();
    if (tid < 32) {
        float a = u_fc_bv[tid];
        for (int k = 0; k < 96; ++k) a += f[k] * u_fcT[k*32 + tid];
        outp[b*96 + 64 + tid] = a;
    } else {
        int e = tid - 32;
        float a = i_fc_bv[e];
        for (int k = 0; k < 96; ++k) a += f[k] * i_fcT[k*32 + e];
        outp[Bn*96 + b*96 + 64 + e] = a;
    }
}

extern "C" void kernel_launch(void* const* d_in, const int* in_sizes, int n_in,
                              void* d_out, int out_size, void* d_ws, size_t ws_size,
                              hipStream_t stream)
{
    const int* urev = (const int*)d_in[0];
    const int* irev = (const int*)d_in[1];
    const int* uids = (const int*)d_in[2];
    const int* iids = (const int*)d_in[3];
    const int* ttype = (const int*)d_in[4];
    const int* tmonth = (const int*)d_in[5];
    const float* gu = (const float*)d_in[6];
    const float* gi = (const float*)d_in[7];
    const float* utab = (const float*)d_in[8];
    const float* itab = (const float*)d_in[9];
    const float* uid_tab = (const float*)d_in[10];
    const float* iid_tab = (const float*)d_in[11];
    const float* type_tab = (const float*)d_in[12];
    const float* month_tab = (const float*)d_in[13];
    const float* fc_g1_w = (const float*)d_in[14];
    const float* fc_g1_b = (const float*)d_in[15];
    const float* fc_g2_w = (const float*)d_in[16];
    const float* fc_g2_b = (const float*)d_in[17];
    const float* M_r = (const float*)d_in[18];
    const float* Wu_r = (const float*)d_in[19];
    const float* bu_r = (const float*)d_in[20];
    const float* Wi_r = (const float*)d_in[21];
    const float* bi_r = (const float*)d_in[22];
    const float* M_w = (const float*)d_in[23];
    const float* Wu_w = (const float*)d_in[24];
    const float* bu_w = (const float*)d_in[25];
    const float* Wi_w = (const float*)d_in[26];
    const float* bi_w = (const float*)d_in[27];
    const float* M_f = (const float*)d_in[28];
    const float* Wu_f = (const float*)d_in[29];
    const float* bu_f = (const float*)d_in[30];
    const float* Wi_f = (const float*)d_in[31];
    const float* bi_f = (const float*)d_in[32];
    const float* ufc_w = (const float*)d_in[33];
    const float* ufc_b = (const float*)d_in[34];
    const float* ifc_w = (const float*)d_in[35];
    const float* ifc_b = (const float*)d_in[36];
    const float* u_fc_w = (const float*)d_in[37];
    const float* u_fc_b = (const float*)d_in[38];
    const float* i_fc_w = (const float*)d_in[39];
    const float* i_fc_b = (const float*)d_in[40];
    (void)in_sizes; (void)n_in; (void)out_size; (void)ws_size;

    float* ws = (float*)d_ws;
    float* ugo   = ws;                        // B*L*D
    float* igo   = ugo + Bn*Ln*Dn;            // B*L*D
    float* feas  = igo + Bn*Ln*Dn;            // B*96
    float* WuT_r = feas + Bn*96;
    float* WiT_r = WuT_r + Hn*Dn*Dn;
    float* WuT_w = WiT_r + Hn*Dn*Dn;
    float* WiT_w = WuT_w + Hn*Dn*Dn;
    float* MT_w  = WiT_w + Hn*Dn*Dn;
    float* WuT_f = MT_w + Hn*Dn*Dn;
    float* WiT_f = WuT_f + Hn*En*En;
    float* ufcT  = WiT_f + Hn*En*En;
    float* ifcT  = ufcT + Dn*En;
    float* u_fcT = ifcT + Dn*En;
    float* i_fcT = u_fcT + 96*En;

    hipLaunchKernelGGL(k0_prep, dim3(32), dim3(256), 0, stream,
        Wu_r, Wi_r, Wu_w, Wi_w, M_w, Wu_f, Wi_f, ufc_w, ifc_w, u_fc_w, i_fc_w,
        WuT_r, WiT_r, WuT_w, WiT_w, MT_w, WuT_f, WiT_f, ufcT, ifcT, u_fcT, i_fcT);

    hipLaunchKernelGGL(k1_gate, dim3(2*Bn*Ln/4), dim3(256), 0, stream,
        urev, irev, utab, itab, fc_g1_w, fc_g1_b, fc_g2_w, fc_g2_b, ugo, igo);

    hipLaunchKernelGGL(k2_coatt, dim3(Bn*Hn), dim3(256), 0, stream,
        urev, irev, uids, iids, ttype, tmonth, gu, gi, utab, itab,
        uid_tab, iid_tab, type_tab, month_tab, ugo, igo,
        M_r, bu_r, bi_r, WuT_r, WiT_r,
        Wu_w, Wi_w, M_w, bu_w, bi_w, WuT_w, WiT_w, MT_w,
        M_f, bu_f, bi_f, WuT_f, WiT_f,
        ufcT, ufc_b, ifcT, ifc_b, feas, (float*)d_out);

    hipLaunchKernelGGL(k3_final, dim3(Bn), dim3(64), 0, stream,
        feas, u_fcT, u_fc_b, i_fcT, i_fc_b, (float*)d_out);
}